// Round 20
// baseline (376.153 us; speedup 1.0000x reference)
//
#include <hip/hip_runtime.h>
#include <hip/hip_bf16.h>
#include <math.h>

#define NN 200000
#define NE 6400000

#define BNODES 782                     // nodes per bucket (NB = 256 = #CUs)
#define NB 256
#define CAP 27648                      // 27*1024; mean 25000 -> +16 sigma
#define NBLK_SC 256
#define SCT 1024                       // scatter/sort block threads (16 waves)
#define CHUNK (NE / NBLK_SC)           // 25000; 25 iters/thread
#define SREG 27                        // sort: CAP/SCT register records/thread
#define GL 8                           // gat: lanes per node

// ---- workspace layout (4-byte words) ----
#define W_DACC 0                       // double (2 words)
#define W_DONE 2                       // 1 uint: gat2 completion counter
#define W_UV   4                       // 8 floats
#define W_CUR  16                      // NB uints
#define W_NOFF 1024                    // NN uints
#define W_NCNT (W_NOFF + NN)           // NN uints
#define W_META (W_NCNT + NN)           // NB*CAP u32: sn(18b) | dl(10b)<<18
#define W_Z2   (W_META + NB*CAP)       // 2*NN f32
#define W_TOTAL (W_Z2 + 2*NN)          // ~7.9M words = 31.5 MB

// init + prep merged: zero dacc/done/cur, compute uv from fc1/attn1
__global__ void k_init(unsigned* __restrict__ ws, const float* __restrict__ fc1,
                       const float* __restrict__ attn1) {
    int t = threadIdx.x;
    if (t == 0) { *(double*)ws = 0.0; ws[W_DONE] = 0u; }
    if (t < NB) ws[W_CUR + t] = 0u;
    if (t >= 256 && t < 264) {
        int q = t - 256;
        int hh = q >> 2, r = q & 3, i = r & 1, isv = r >> 1;
        double s = 0.0;
        for (int o = 0; o < 16; ++o)
            s += (double)fc1[hh * 32 + i * 16 + o] * (double)attn1[hh * 32 + isv * 16 + o];
        ((float*)(ws + W_UV))[q] = (float)s;
    }
}

// radix partition by dst bucket (b = d/782), 4B meta records, ONE LDS atomic/edge.
__launch_bounds__(SCT)
__global__ void k_scatter(const int* __restrict__ src, const int* __restrict__ dst,
                          unsigned* __restrict__ meta, unsigned* __restrict__ cur) {
    __shared__ unsigned cnt[NB], gbase[NB];           // 2 KB
    for (int i = threadIdx.x; i < NB; i += SCT) cnt[i] = 0u;
    __syncthreads();
    int beg = blockIdx.x * CHUNK;
    unsigned pack[25];                                // d(18b) | rank(14b)<<18
#pragma unroll
    for (int k = 0; k < 25; ++k) {
        int j = k * SCT + threadIdx.x;
        pack[k] = 0xFFFFFFFFu;                        // d-field 0x3FFFF impossible (d<200000)
        if (j < CHUNK) {
            unsigned d = (unsigned)__builtin_nontemporal_load(dst + beg + j);
            unsigned rank = atomicAdd(&cnt[d / BNODES], 1u);   // count == rank
            pack[k] = d | (rank << 18);
        }
    }
    __syncthreads();
    for (int i = threadIdx.x; i < NB; i += SCT)
        gbase[i] = cnt[i] ? atomicAdd(&cur[i], cnt[i]) : 0u;
    __syncthreads();
#pragma unroll
    for (int k = 0; k < 25; ++k) {
        if (pack[k] != 0xFFFFFFFFu) {
            int j = k * SCT + threadIdx.x;
            unsigned d = pack[k] & 0x3FFFFu;
            unsigned b = d / BNODES;
            unsigned dl = d - b * BNODES;
            unsigned slot = gbase[b] + (pack[k] >> 18);
            if (slot < CAP) {
                unsigned sn = (unsigned)__builtin_nontemporal_load(src + beg + j);
                meta[(size_t)b * CAP + slot] = sn | (dl << 18);
            }
        }
    }
}

// in-place counting sort by node within each bucket; 256 blocks (1/CU, balanced);
// records staged in registers (27/thread, static); ONE LDS atomic/edge.
__launch_bounds__(SCT)
__global__ void k_sort(unsigned* __restrict__ meta, const unsigned* __restrict__ cur,
                       unsigned* __restrict__ nodeoff, unsigned* __restrict__ nodecnt) {
    __shared__ unsigned hist[BNODES], base[BNODES], scan[BNODES];   // 9.4 KB
    int b = blockIdx.x, t = threadIdx.x;
    size_t boff = (size_t)b * CAP;
    int cnt = min((int)cur[b], CAP);
    for (int i = t; i < BNODES; i += SCT) hist[i] = 0u;
    __syncthreads();
    unsigned rm[SREG], rr[SREG];
#pragma unroll
    for (int k = 0; k < SREG; ++k) {
        int i = k * SCT + t;
        rm[k] = 0xFFFFFFFFu;
        rr[k] = 0u;
        if (i < cnt) {
            rm[k] = meta[boff + i];
            rr[k] = atomicAdd(&hist[rm[k] >> 18], 1u);    // rank within node
        }
    }
    asm volatile("s_waitcnt vmcnt(0)" ::: "memory");      // all reads before any write
    __syncthreads();
    if (t < BNODES) scan[t] = hist[t];
    __syncthreads();
    for (int d = 1; d < BNODES; d <<= 1) {                // Hillis-Steele inclusive scan
        unsigned v = 0u;
        if (t < BNODES && t >= d) v = scan[t - d];
        __syncthreads();
        if (t < BNODES) scan[t] += v;
        __syncthreads();
    }
    int nb = b * BNODES;
    int nn = min(BNODES, NN - nb);
    if (t < BNODES) {
        unsigned ex = scan[t] - hist[t];                  // exclusive base
        base[t] = ex;
        if (t < nn) {
            nodeoff[nb + t] = (unsigned)boff + ex;
            nodecnt[nb + t] = hist[t];
        }
    }
    __syncthreads();
#pragma unroll
    for (int k = 0; k < SREG; ++k)
        if (rm[k] != 0xFFFFFFFFu)
            meta[boff + base[rm[k] >> 18] + rr[k]] = rm[k];
}

// layer-1 + node finalize: 8 lanes per node (TLP 12->32+ waves/CU), zero atomics.
// Per-iteration meta reads are coalesced across the 8-lane group.
__global__ void k_gat1(const unsigned* __restrict__ meta, const unsigned* __restrict__ nodeoff,
                       const unsigned* __restrict__ nodecnt, const float2* __restrict__ h,
                       const float* __restrict__ uv, const float* __restrict__ fc1,
                       const float* __restrict__ fc2, float2* __restrict__ z2) {
    int gid = blockIdx.x * blockDim.x + threadIdx.x;
    int n = gid >> 3, sub = gid & (GL - 1);
    if (n >= NN) return;
    float u00 = uv[0], u10 = uv[1], v00 = uv[2], v10 = uv[3];
    float u01 = uv[4], u11 = uv[5], v01 = uv[6], v11 = uv[7];
    float2 hd = h[n];
    float c0 = fmaf(hd.x, v00, hd.y * v10);
    float c1 = fmaf(hd.x, v01, hd.y * v11);
    unsigned off = nodeoff[n];
    int cnt = (int)nodecnt[n];
    float s0 = 0.f, s1 = 0.f, s2 = 0.f, s3 = 0.f, s4 = 0.f, s5 = 0.f;
    for (int k = sub; k < cnt; k += GL) {
        unsigned m = meta[(size_t)off + k];
        float2 hs = h[m & 0x3FFFF];
        float e0 = fmaf(hs.x, u00, fmaf(hs.y, u10, c0));
        float e1 = fmaf(hs.x, u01, fmaf(hs.y, u11, c1));
        e0 = e0 >= 0.f ? e0 : 0.01f * e0;
        e1 = e1 >= 0.f ? e1 : 0.01f * e1;
        float ex0 = __expf(e0);
        float ex1 = __expf(e1);
        s0 += ex0; s1 += ex0 * hs.x; s2 += ex0 * hs.y;
        s3 += ex1; s4 += ex1 * hs.x; s5 += ex1 * hs.y;
    }
#pragma unroll
    for (int m = 1; m < GL; m <<= 1) {        // reduce within the 8-lane group
        s0 += __shfl_xor(s0, m);
        s1 += __shfl_xor(s1, m);
        s2 += __shfl_xor(s2, m);
        s3 += __shfl_xor(s3, m);
        s4 += __shfl_xor(s4, m);
        s5 += __shfl_xor(s5, m);
    }
    if (sub == 0) {
        float z0 = 0.f, z1 = 0.f;
#pragma unroll
        for (int o = 0; o < 16; ++o) {        // softmax div + elu + z2 = x @ fc2
            float t0 = s0 > 0.f ? (s1 * fc1[o]      + s2 * fc1[16 + o]) / s0 : 0.f;
            float t1 = s3 > 0.f ? (s4 * fc1[32 + o] + s5 * fc1[48 + o]) / s3 : 0.f;
            float x0 = t0 > 0.f ? t0 : expm1f(t0);
            float x1 = t1 > 0.f ? t1 : expm1f(t1);
            z0 += x0 * fc2[2 * o]     + x1 * fc2[2 * (16 + o)];
            z1 += x0 * fc2[2 * o + 1] + x1 * fc2[2 * (16 + o) + 1];
        }
        z2[n] = make_float2(z0, z1);
    }
}

// layer-2 + MLP dot: 8 lanes per node; f64 block reduce; LAST block -> sigmoid.
__global__ void k_gat2(const unsigned* __restrict__ meta, const unsigned* __restrict__ nodeoff,
                       const unsigned* __restrict__ nodecnt, const float2* __restrict__ z2,
                       const float* __restrict__ attn2, const float* __restrict__ mlp_w,
                       const float* __restrict__ mlp_b, double* __restrict__ dacc,
                       unsigned* __restrict__ done, float* __restrict__ out) {
    int gid = blockIdx.x * blockDim.x + threadIdx.x;
    int n = gid >> 3, sub = gid & (GL - 1);
    double v = 0.0;
    if (n < NN) {
        float a0 = attn2[0], a1 = attn2[1], a2 = attn2[2], a3 = attn2[3];
        float2 zd = z2[n];
        float cd = fmaf(zd.x, a2, zd.y * a3);
        unsigned off = nodeoff[n];
        int cnt = (int)nodecnt[n];
        float s0 = 0.f, s1 = 0.f, s2 = 0.f;
        for (int k = sub; k < cnt; k += GL) {
            unsigned m = meta[(size_t)off + k];
            float2 zs = z2[m & 0x3FFFF];
            float e = fmaf(zs.x, a0, fmaf(zs.y, a1, cd));
            e = e >= 0.f ? e : 0.01f * e;
            float ex = __expf(e - 48.f);   // const shift cancels; e<=~88, den>=deg*e^-49
            s0 += ex; s1 += ex * zs.x; s2 += ex * zs.y;
        }
#pragma unroll
        for (int m = 1; m < GL; m <<= 1) {
            s0 += __shfl_xor(s0, m);
            s1 += __shfl_xor(s1, m);
            s2 += __shfl_xor(s2, m);
        }
        if (sub == 0) {
            float x0 = s0 > 0.f ? s1 / s0 : 0.f;
            float x1 = s0 > 0.f ? s2 / s0 : 0.f;
            v = (double)x0 * (double)mlp_w[2 * n] + (double)x1 * (double)mlp_w[2 * n + 1];
        }
    }
    for (int off = 32; off > 0; off >>= 1) v += __shfl_down(v, off);
    __shared__ double sm[4];
    int lane = threadIdx.x & 63, wid = threadIdx.x >> 6;
    if (lane == 0) sm[wid] = v;
    __syncthreads();
    if (threadIdx.x == 0) {
        double sum = sm[0] + sm[1] + sm[2] + sm[3];
        unsafeAtomicAdd(dacc, sum);                  // device-scope, memory-side
        __threadfence();                             // dacc-add visible before counter
        unsigned prev = atomicAdd(done, 1u);         // device-scope counter
        if (prev == gridDim.x - 1) {                 // last block: all sums landed
            __threadfence();
            double logit = __hip_atomic_load(dacc, __ATOMIC_RELAXED,
                                             __HIP_MEMORY_SCOPE_AGENT) +
                           (double)mlp_b[0];
            out[0] = (float)(1.0 / (1.0 + exp(-logit)));
        }
    }
}

extern "C" void kernel_launch(void* const* d_in, const int* in_sizes, int n_in,
                              void* d_out, int out_size, void* d_ws, size_t ws_size,
                              hipStream_t stream) {
    const float2* h    = (const float2*)d_in[0];
    const int*   src   = (const int*)d_in[1];
    const int*   dst   = (const int*)d_in[2];
    const float* fc1   = (const float*)d_in[3];
    const float* attn1 = (const float*)d_in[4];
    const float* fc2   = (const float*)d_in[5];
    const float* attn2 = (const float*)d_in[6];
    const float* mlp_w = (const float*)d_in[7];
    const float* mlp_b = (const float*)d_in[8];
    float* out = (float*)d_out;

    unsigned* ws      = (unsigned*)d_ws;
    double*   dacc    = (double*)d_ws;
    unsigned* done    = ws + W_DONE;
    float*    uv      = (float*)(ws + W_UV);
    unsigned* cur     = ws + W_CUR;
    unsigned* nodeoff = ws + W_NOFF;
    unsigned* nodecnt = ws + W_NCNT;
    unsigned* meta    = ws + W_META;
    float2*   z2      = (float2*)(ws + W_Z2);

    const int NGG = (NN * GL + 255) / 256;      // 6250 blocks for gat kernels

    hipLaunchKernelGGL(k_init, dim3(1), dim3(264), 0, stream, ws, fc1, attn1);
    hipLaunchKernelGGL(k_scatter, dim3(NBLK_SC), dim3(SCT), 0, stream,
                       src, dst, meta, cur);
    hipLaunchKernelGGL(k_sort, dim3(NB), dim3(SCT), 0, stream,
                       meta, cur, nodeoff, nodecnt);
    hipLaunchKernelGGL(k_gat1, dim3(NGG), dim3(256), 0, stream,
                       meta, nodeoff, nodecnt, (const float2*)h, uv, fc1, fc2, z2);
    hipLaunchKernelGGL(k_gat2, dim3(NGG), dim3(256), 0, stream,
                       meta, nodeoff, nodecnt, (const float2*)z2, attn2, mlp_w,
                       mlp_b, dacc, done, out);
}

// Round 21
// 349.137 us; speedup vs baseline: 1.0774x; 1.0774x over previous
//
#include <hip/hip_runtime.h>
#include <hip/hip_bf16.h>
#include <math.h>

#define NN 200000
#define NE 6400000

#define BNODES 782                     // nodes per bucket (NB = 256 = #CUs)
#define NB 256
#define CAP 27648                      // 27*1024; mean 25000 -> +16 sigma
#define NBLK_SC 256
#define SCT 1024                       // scatter/sort block threads (16 waves)
#define CHUNK (NE / NBLK_SC)           // 25000; 25 iters/thread
#define SREG 27                        // sort: CAP/SCT register records/thread
#define GL 8                           // gat: lanes per node

// ---- workspace layout (4-byte words) ----
#define W_DACC 0                       // double (2 words)
#define W_DONE 2                       // 1 uint: gat2 completion counter
#define W_UV   4                       // 8 floats
#define W_CUR  16                      // NB uints
#define W_NOFF 1024                    // NN uints
#define W_NCNT (W_NOFF + NN)           // NN uints
#define W_META (W_NCNT + NN)           // NB*CAP u32: sn(18b) | dl(10b)<<18
#define W_Z2   (W_META + NB*CAP)       // 2*NN f32
#define W_TOTAL (W_Z2 + 2*NN)          // ~7.9M words = 31.5 MB

// init + prep merged: zero dacc/done/cur, compute uv from fc1/attn1
__global__ void k_init(unsigned* __restrict__ ws, const float* __restrict__ fc1,
                       const float* __restrict__ attn1) {
    int t = threadIdx.x;
    if (t == 0) { *(double*)ws = 0.0; ws[W_DONE] = 0u; }
    if (t < NB) ws[W_CUR + t] = 0u;
    if (t >= 256 && t < 264) {
        int q = t - 256;
        int hh = q >> 2, r = q & 3, i = r & 1, isv = r >> 1;
        double s = 0.0;
        for (int o = 0; o < 16; ++o)
            s += (double)fc1[hh * 32 + i * 16 + o] * (double)attn1[hh * 32 + isv * 16 + o];
        ((float*)(ws + W_UV))[q] = (float)s;
    }
}

// radix partition by dst bucket (b = d/782), 4B meta records, ONE LDS atomic/edge.
__launch_bounds__(SCT)
__global__ void k_scatter(const int* __restrict__ src, const int* __restrict__ dst,
                          unsigned* __restrict__ meta, unsigned* __restrict__ cur) {
    __shared__ unsigned cnt[NB], gbase[NB];           // 2 KB
    for (int i = threadIdx.x; i < NB; i += SCT) cnt[i] = 0u;
    __syncthreads();
    int beg = blockIdx.x * CHUNK;
    unsigned pack[25];                                // d(18b) | rank(14b)<<18
#pragma unroll
    for (int k = 0; k < 25; ++k) {
        int j = k * SCT + threadIdx.x;
        pack[k] = 0xFFFFFFFFu;                        // d-field 0x3FFFF impossible (d<200000)
        if (j < CHUNK) {
            unsigned d = (unsigned)__builtin_nontemporal_load(dst + beg + j);
            unsigned rank = atomicAdd(&cnt[d / BNODES], 1u);   // count == rank
            pack[k] = d | (rank << 18);
        }
    }
    __syncthreads();
    for (int i = threadIdx.x; i < NB; i += SCT)
        gbase[i] = cnt[i] ? atomicAdd(&cur[i], cnt[i]) : 0u;
    __syncthreads();
#pragma unroll
    for (int k = 0; k < 25; ++k) {
        if (pack[k] != 0xFFFFFFFFu) {
            int j = k * SCT + threadIdx.x;
            unsigned d = pack[k] & 0x3FFFFu;
            unsigned b = d / BNODES;
            unsigned dl = d - b * BNODES;
            unsigned slot = gbase[b] + (pack[k] >> 18);
            if (slot < CAP) {
                unsigned sn = (unsigned)__builtin_nontemporal_load(src + beg + j);
                meta[(size_t)b * CAP + slot] = sn | (dl << 18);
            }
        }
    }
}

// in-place counting sort by node within each bucket; 256 blocks (1/CU, balanced);
// records staged in registers (27/thread, static); ONE LDS atomic/edge.
__launch_bounds__(SCT)
__global__ void k_sort(unsigned* __restrict__ meta, const unsigned* __restrict__ cur,
                       unsigned* __restrict__ nodeoff, unsigned* __restrict__ nodecnt) {
    __shared__ unsigned hist[BNODES], base[BNODES], scan[BNODES];   // 9.4 KB
    int b = blockIdx.x, t = threadIdx.x;
    size_t boff = (size_t)b * CAP;
    int cnt = min((int)cur[b], CAP);
    for (int i = t; i < BNODES; i += SCT) hist[i] = 0u;
    __syncthreads();
    unsigned rm[SREG], rr[SREG];
#pragma unroll
    for (int k = 0; k < SREG; ++k) {
        int i = k * SCT + t;
        rm[k] = 0xFFFFFFFFu;
        rr[k] = 0u;
        if (i < cnt) {
            rm[k] = meta[boff + i];
            rr[k] = atomicAdd(&hist[rm[k] >> 18], 1u);    // rank within node
        }
    }
    asm volatile("s_waitcnt vmcnt(0)" ::: "memory");      // all reads before any write
    __syncthreads();
    if (t < BNODES) scan[t] = hist[t];
    __syncthreads();
    for (int d = 1; d < BNODES; d <<= 1) {                // Hillis-Steele inclusive scan
        unsigned v = 0u;
        if (t < BNODES && t >= d) v = scan[t - d];
        __syncthreads();
        if (t < BNODES) scan[t] += v;
        __syncthreads();
    }
    int nb = b * BNODES;
    int nn = min(BNODES, NN - nb);
    if (t < BNODES) {
        unsigned ex = scan[t] - hist[t];                  // exclusive base
        base[t] = ex;
        if (t < nn) {
            nodeoff[nb + t] = (unsigned)boff + ex;
            nodecnt[nb + t] = hist[t];
        }
    }
    __syncthreads();
#pragma unroll
    for (int k = 0; k < SREG; ++k)
        if (rm[k] != 0xFFFFFFFFu)
            meta[boff + base[rm[k] >> 18] + rr[k]] = rm[k];
}

// layer-1 + node finalize: 8 lanes per node, zero atomics, NO fences.
__global__ void k_gat1(const unsigned* __restrict__ meta, const unsigned* __restrict__ nodeoff,
                       const unsigned* __restrict__ nodecnt, const float2* __restrict__ h,
                       const float* __restrict__ uv, const float* __restrict__ fc1,
                       const float* __restrict__ fc2, float2* __restrict__ z2) {
    int gid = blockIdx.x * blockDim.x + threadIdx.x;
    int n = gid >> 3, sub = gid & (GL - 1);
    if (n >= NN) return;
    float u00 = uv[0], u10 = uv[1], v00 = uv[2], v10 = uv[3];
    float u01 = uv[4], u11 = uv[5], v01 = uv[6], v11 = uv[7];
    float2 hd = h[n];
    float c0 = fmaf(hd.x, v00, hd.y * v10);
    float c1 = fmaf(hd.x, v01, hd.y * v11);
    unsigned off = nodeoff[n];
    int cnt = (int)nodecnt[n];
    float s0 = 0.f, s1 = 0.f, s2 = 0.f, s3 = 0.f, s4 = 0.f, s5 = 0.f;
    for (int k = sub; k < cnt; k += GL) {
        unsigned m = meta[(size_t)off + k];
        float2 hs = h[m & 0x3FFFF];
        float e0 = fmaf(hs.x, u00, fmaf(hs.y, u10, c0));
        float e1 = fmaf(hs.x, u01, fmaf(hs.y, u11, c1));
        e0 = e0 >= 0.f ? e0 : 0.01f * e0;
        e1 = e1 >= 0.f ? e1 : 0.01f * e1;
        float ex0 = __expf(e0);
        float ex1 = __expf(e1);
        s0 += ex0; s1 += ex0 * hs.x; s2 += ex0 * hs.y;
        s3 += ex1; s4 += ex1 * hs.x; s5 += ex1 * hs.y;
    }
#pragma unroll
    for (int m = 1; m < GL; m <<= 1) {        // reduce within the 8-lane group
        s0 += __shfl_xor(s0, m);
        s1 += __shfl_xor(s1, m);
        s2 += __shfl_xor(s2, m);
        s3 += __shfl_xor(s3, m);
        s4 += __shfl_xor(s4, m);
        s5 += __shfl_xor(s5, m);
    }
    if (sub == 0) {
        float z0 = 0.f, z1 = 0.f;
#pragma unroll
        for (int o = 0; o < 16; ++o) {        // softmax div + elu + z2 = x @ fc2
            float t0 = s0 > 0.f ? (s1 * fc1[o]      + s2 * fc1[16 + o]) / s0 : 0.f;
            float t1 = s3 > 0.f ? (s4 * fc1[32 + o] + s5 * fc1[48 + o]) / s3 : 0.f;
            float x0 = t0 > 0.f ? t0 : expm1f(t0);
            float x1 = t1 > 0.f ? t1 : expm1f(t1);
            z0 += x0 * fc2[2 * o]     + x1 * fc2[2 * (16 + o)];
            z1 += x0 * fc2[2 * o + 1] + x1 * fc2[2 * (16 + o) + 1];
        }
        z2[n] = make_float2(z0, z1);
    }
}

// layer-2 + MLP dot: 8 lanes per node; f64 block reduce; LAST block -> sigmoid.
// NO __threadfence (L2 wb/inv storm was the r20 regression): the dacc atomic is
// memory-side; s_waitcnt vmcnt(0) orders it before the done-counter increment.
__global__ void k_gat2(const unsigned* __restrict__ meta, const unsigned* __restrict__ nodeoff,
                       const unsigned* __restrict__ nodecnt, const float2* __restrict__ z2,
                       const float* __restrict__ attn2, const float* __restrict__ mlp_w,
                       const float* __restrict__ mlp_b, double* __restrict__ dacc,
                       unsigned* __restrict__ done, float* __restrict__ out) {
    int gid = blockIdx.x * blockDim.x + threadIdx.x;
    int n = gid >> 3, sub = gid & (GL - 1);
    double v = 0.0;
    if (n < NN) {
        float a0 = attn2[0], a1 = attn2[1], a2 = attn2[2], a3 = attn2[3];
        float2 zd = z2[n];
        float cd = fmaf(zd.x, a2, zd.y * a3);
        unsigned off = nodeoff[n];
        int cnt = (int)nodecnt[n];
        float s0 = 0.f, s1 = 0.f, s2 = 0.f;
        for (int k = sub; k < cnt; k += GL) {
            unsigned m = meta[(size_t)off + k];
            float2 zs = z2[m & 0x3FFFF];
            float e = fmaf(zs.x, a0, fmaf(zs.y, a1, cd));
            e = e >= 0.f ? e : 0.01f * e;
            float ex = __expf(e - 48.f);   // const shift cancels; e<=~88, den>=deg*e^-49
            s0 += ex; s1 += ex * zs.x; s2 += ex * zs.y;
        }
#pragma unroll
        for (int m = 1; m < GL; m <<= 1) {
            s0 += __shfl_xor(s0, m);
            s1 += __shfl_xor(s1, m);
            s2 += __shfl_xor(s2, m);
        }
        if (sub == 0) {
            float x0 = s0 > 0.f ? s1 / s0 : 0.f;
            float x1 = s0 > 0.f ? s2 / s0 : 0.f;
            v = (double)x0 * (double)mlp_w[2 * n] + (double)x1 * (double)mlp_w[2 * n + 1];
        }
    }
    for (int off = 32; off > 0; off >>= 1) v += __shfl_down(v, off);
    __shared__ double sm[4];
    int lane = threadIdx.x & 63, wid = threadIdx.x >> 6;
    if (lane == 0) sm[wid] = v;
    __syncthreads();
    if (threadIdx.x == 0) {
        double sum = sm[0] + sm[1] + sm[2] + sm[3];
        unsafeAtomicAdd(dacc, sum);                       // memory-side f64 atomic
        asm volatile("s_waitcnt vmcnt(0)" ::: "memory");  // atomic acknowledged
        unsigned prev = atomicAdd(done, 1u);              // memory-side counter
        if (prev == gridDim.x - 1) {                      // last block: all adds landed
            double logit = __hip_atomic_load(dacc, __ATOMIC_ACQUIRE,
                                             __HIP_MEMORY_SCOPE_AGENT) +
                           (double)mlp_b[0];
            out[0] = (float)(1.0 / (1.0 + exp(-logit)));
        }
    }
}

extern "C" void kernel_launch(void* const* d_in, const int* in_sizes, int n_in,
                              void* d_out, int out_size, void* d_ws, size_t ws_size,
                              hipStream_t stream) {
    const float2* h    = (const float2*)d_in[0];
    const int*   src   = (const int*)d_in[1];
    const int*   dst   = (const int*)d_in[2];
    const float* fc1   = (const float*)d_in[3];
    const float* attn1 = (const float*)d_in[4];
    const float* fc2   = (const float*)d_in[5];
    const float* attn2 = (const float*)d_in[6];
    const float* mlp_w = (const float*)d_in[7];
    const float* mlp_b = (const float*)d_in[8];
    float* out = (float*)d_out;

    unsigned* ws      = (unsigned*)d_ws;
    double*   dacc    = (double*)d_ws;
    unsigned* done    = ws + W_DONE;
    float*    uv      = (float*)(ws + W_UV);
    unsigned* cur     = ws + W_CUR;
    unsigned* nodeoff = ws + W_NOFF;
    unsigned* nodecnt = ws + W_NCNT;
    unsigned* meta    = ws + W_META;
    float2*   z2      = (float2*)(ws + W_Z2);

    const int NGG = (NN * GL + 255) / 256;      // 6250 blocks for gat kernels

    hipLaunchKernelGGL(k_init, dim3(1), dim3(264), 0, stream, ws, fc1, attn1);
    hipLaunchKernelGGL(k_scatter, dim3(NBLK_SC), dim3(SCT), 0, stream,
                       src, dst, meta, cur);
    hipLaunchKernelGGL(k_sort, dim3(NB), dim3(SCT), 0, stream,
                       meta, cur, nodeoff, nodecnt);
    hipLaunchKernelGGL(k_gat1, dim3(NGG), dim3(256), 0, stream,
                       meta, nodeoff, nodecnt, (const float2*)h, uv, fc1, fc2, z2);
    hipLaunchKernelGGL(k_gat2, dim3(NGG), dim3(256), 0, stream,
                       meta, nodeoff, nodecnt, (const float2*)z2, attn2, mlp_w,
                       mlp_b, dacc, done, out);
}

// Round 22
// 279.758 us; speedup vs baseline: 1.3446x; 1.2480x over previous
//
#include <hip/hip_runtime.h>
#include <hip/hip_bf16.h>
#include <math.h>

#define NN 200000
#define NE 6400000

#define BNODES 782                     // nodes per bucket (NB = 256 = #CUs)
#define NB 256
#define CAP 27648                      // 27*1024; mean 25000 -> +16 sigma
#define NBLK_SC 256
#define SCT 1024                       // scatter/sort block threads (16 waves)
#define CHUNK (NE / NBLK_SC)           // 25000; 25 iters/thread
#define SREG 27                        // sort: CAP/SCT register records/thread
#define GL 8                           // gat: lanes per node

// ---- workspace layout (4-byte words) ----
#define W_DACC 0                       // double (2 words)
#define W_UV   4                       // 8 floats
#define W_CUR  16                      // NB uints
#define W_NOFF 1024                    // NN uints
#define W_NCNT (W_NOFF + NN)           // NN uints
#define W_META (W_NCNT + NN)           // NB*CAP u32: sn(18b) | dl(10b)<<18
#define W_Z2   (W_META + NB*CAP)       // 2*NN f32
#define W_TOTAL (W_Z2 + 2*NN)          // ~7.9M words = 31.5 MB

// init + prep merged: zero dacc/cur, compute uv from fc1/attn1
__global__ void k_init(unsigned* __restrict__ ws, const float* __restrict__ fc1,
                       const float* __restrict__ attn1) {
    int t = threadIdx.x;
    if (t == 0) *(double*)ws = 0.0;
    if (t < NB) ws[W_CUR + t] = 0u;
    if (t >= 256 && t < 264) {
        int q = t - 256;
        int hh = q >> 2, r = q & 3, i = r & 1, isv = r >> 1;
        double s = 0.0;
        for (int o = 0; o < 16; ++o)
            s += (double)fc1[hh * 32 + i * 16 + o] * (double)attn1[hh * 32 + isv * 16 + o];
        ((float*)(ws + W_UV))[q] = (float)s;
    }
}

// radix partition by dst bucket (b = d/782), 4B meta records, ONE LDS atomic/edge.
__launch_bounds__(SCT)
__global__ void k_scatter(const int* __restrict__ src, const int* __restrict__ dst,
                          unsigned* __restrict__ meta, unsigned* __restrict__ cur) {
    __shared__ unsigned cnt[NB], gbase[NB];           // 2 KB
    for (int i = threadIdx.x; i < NB; i += SCT) cnt[i] = 0u;
    __syncthreads();
    int beg = blockIdx.x * CHUNK;
    unsigned pack[25];                                // d(18b) | rank(14b)<<18
#pragma unroll
    for (int k = 0; k < 25; ++k) {
        int j = k * SCT + threadIdx.x;
        pack[k] = 0xFFFFFFFFu;                        // d-field 0x3FFFF impossible (d<200000)
        if (j < CHUNK) {
            unsigned d = (unsigned)__builtin_nontemporal_load(dst + beg + j);
            unsigned rank = atomicAdd(&cnt[d / BNODES], 1u);   // count == rank
            pack[k] = d | (rank << 18);
        }
    }
    __syncthreads();
    for (int i = threadIdx.x; i < NB; i += SCT)
        gbase[i] = cnt[i] ? atomicAdd(&cur[i], cnt[i]) : 0u;
    __syncthreads();
#pragma unroll
    for (int k = 0; k < 25; ++k) {
        if (pack[k] != 0xFFFFFFFFu) {
            int j = k * SCT + threadIdx.x;
            unsigned d = pack[k] & 0x3FFFFu;
            unsigned b = d / BNODES;
            unsigned dl = d - b * BNODES;
            unsigned slot = gbase[b] + (pack[k] >> 18);
            if (slot < CAP) {
                unsigned sn = (unsigned)__builtin_nontemporal_load(src + beg + j);
                meta[(size_t)b * CAP + slot] = sn | (dl << 18);
            }
        }
    }
}

// in-place counting sort by node within each bucket; 256 blocks (1/CU, balanced);
// records staged in registers (27/thread, static); ONE LDS atomic/edge.
__launch_bounds__(SCT)
__global__ void k_sort(unsigned* __restrict__ meta, const unsigned* __restrict__ cur,
                       unsigned* __restrict__ nodeoff, unsigned* __restrict__ nodecnt) {
    __shared__ unsigned hist[BNODES], base[BNODES], scan[BNODES];   // 9.4 KB
    int b = blockIdx.x, t = threadIdx.x;
    size_t boff = (size_t)b * CAP;
    int cnt = min((int)cur[b], CAP);
    for (int i = t; i < BNODES; i += SCT) hist[i] = 0u;
    __syncthreads();
    unsigned rm[SREG], rr[SREG];
#pragma unroll
    for (int k = 0; k < SREG; ++k) {
        int i = k * SCT + t;
        rm[k] = 0xFFFFFFFFu;
        rr[k] = 0u;
        if (i < cnt) {
            rm[k] = meta[boff + i];
            rr[k] = atomicAdd(&hist[rm[k] >> 18], 1u);    // rank within node
        }
    }
    asm volatile("s_waitcnt vmcnt(0)" ::: "memory");      // all reads before any write
    __syncthreads();
    if (t < BNODES) scan[t] = hist[t];
    __syncthreads();
    for (int d = 1; d < BNODES; d <<= 1) {                // Hillis-Steele inclusive scan
        unsigned v = 0u;
        if (t < BNODES && t >= d) v = scan[t - d];
        __syncthreads();
        if (t < BNODES) scan[t] += v;
        __syncthreads();
    }
    int nb = b * BNODES;
    int nn = min(BNODES, NN - nb);
    if (t < BNODES) {
        unsigned ex = scan[t] - hist[t];                  // exclusive base
        base[t] = ex;
        if (t < nn) {
            nodeoff[nb + t] = (unsigned)boff + ex;
            nodecnt[nb + t] = hist[t];
        }
    }
    __syncthreads();
#pragma unroll
    for (int k = 0; k < SREG; ++k)
        if (rm[k] != 0xFFFFFFFFu)
            meta[boff + base[rm[k] >> 18] + rr[k]] = rm[k];
}

// layer-1 + node finalize: 8 lanes per node, zero atomics, no protocol.
__global__ void k_gat1(const unsigned* __restrict__ meta, const unsigned* __restrict__ nodeoff,
                       const unsigned* __restrict__ nodecnt, const float2* __restrict__ h,
                       const float* __restrict__ uv, const float* __restrict__ fc1,
                       const float* __restrict__ fc2, float2* __restrict__ z2) {
    int gid = blockIdx.x * blockDim.x + threadIdx.x;
    int n = gid >> 3, sub = gid & (GL - 1);
    if (n >= NN) return;
    float u00 = uv[0], u10 = uv[1], v00 = uv[2], v10 = uv[3];
    float u01 = uv[4], u11 = uv[5], v01 = uv[6], v11 = uv[7];
    float2 hd = h[n];
    float c0 = fmaf(hd.x, v00, hd.y * v10);
    float c1 = fmaf(hd.x, v01, hd.y * v11);
    unsigned off = nodeoff[n];
    int cnt = (int)nodecnt[n];
    float s0 = 0.f, s1 = 0.f, s2 = 0.f, s3 = 0.f, s4 = 0.f, s5 = 0.f;
    for (int k = sub; k < cnt; k += GL) {
        unsigned m = meta[(size_t)off + k];
        float2 hs = h[m & 0x3FFFF];
        float e0 = fmaf(hs.x, u00, fmaf(hs.y, u10, c0));
        float e1 = fmaf(hs.x, u01, fmaf(hs.y, u11, c1));
        e0 = e0 >= 0.f ? e0 : 0.01f * e0;
        e1 = e1 >= 0.f ? e1 : 0.01f * e1;
        float ex0 = __expf(e0);
        float ex1 = __expf(e1);
        s0 += ex0; s1 += ex0 * hs.x; s2 += ex0 * hs.y;
        s3 += ex1; s4 += ex1 * hs.x; s5 += ex1 * hs.y;
    }
#pragma unroll
    for (int m = 1; m < GL; m <<= 1) {        // reduce within the 8-lane group
        s0 += __shfl_xor(s0, m);
        s1 += __shfl_xor(s1, m);
        s2 += __shfl_xor(s2, m);
        s3 += __shfl_xor(s3, m);
        s4 += __shfl_xor(s4, m);
        s5 += __shfl_xor(s5, m);
    }
    if (sub == 0) {
        float z0 = 0.f, z1 = 0.f;
#pragma unroll
        for (int o = 0; o < 16; ++o) {        // softmax div + elu + z2 = x @ fc2
            float t0 = s0 > 0.f ? (s1 * fc1[o]      + s2 * fc1[16 + o]) / s0 : 0.f;
            float t1 = s3 > 0.f ? (s4 * fc1[32 + o] + s5 * fc1[48 + o]) / s3 : 0.f;
            float x0 = t0 > 0.f ? t0 : expm1f(t0);
            float x1 = t1 > 0.f ? t1 : expm1f(t1);
            z0 += x0 * fc2[2 * o]     + x1 * fc2[2 * (16 + o)];
            z1 += x0 * fc2[2 * o + 1] + x1 * fc2[2 * (16 + o) + 1];
        }
        z2[n] = make_float2(z0, z1);
    }
}

// layer-2 + MLP dot: 8 lanes per node; f64 block reduce; ONE fire-and-forget
// dacc atomic per block (no waitcnt / no done counter / no out-write: the
// r20/r21 regression was blocks waiting on the atomic ack before retiring).
__global__ void k_gat2(const unsigned* __restrict__ meta, const unsigned* __restrict__ nodeoff,
                       const unsigned* __restrict__ nodecnt, const float2* __restrict__ z2,
                       const float* __restrict__ attn2, const float* __restrict__ mlp_w,
                       double* __restrict__ dacc) {
    int gid = blockIdx.x * blockDim.x + threadIdx.x;
    int n = gid >> 3, sub = gid & (GL - 1);
    double v = 0.0;
    if (n < NN) {
        float a0 = attn2[0], a1 = attn2[1], a2 = attn2[2], a3 = attn2[3];
        float2 zd = z2[n];
        float cd = fmaf(zd.x, a2, zd.y * a3);
        unsigned off = nodeoff[n];
        int cnt = (int)nodecnt[n];
        float s0 = 0.f, s1 = 0.f, s2 = 0.f;
        for (int k = sub; k < cnt; k += GL) {
            unsigned m = meta[(size_t)off + k];
            float2 zs = z2[m & 0x3FFFF];
            float e = fmaf(zs.x, a0, fmaf(zs.y, a1, cd));
            e = e >= 0.f ? e : 0.01f * e;
            float ex = __expf(e - 48.f);   // const shift cancels; e<=~88, den>=deg*e^-49
            s0 += ex; s1 += ex * zs.x; s2 += ex * zs.y;
        }
#pragma unroll
        for (int m = 1; m < GL; m <<= 1) {
            s0 += __shfl_xor(s0, m);
            s1 += __shfl_xor(s1, m);
            s2 += __shfl_xor(s2, m);
        }
        if (sub == 0) {
            float x0 = s0 > 0.f ? s1 / s0 : 0.f;
            float x1 = s0 > 0.f ? s2 / s0 : 0.f;
            v = (double)x0 * (double)mlp_w[2 * n] + (double)x1 * (double)mlp_w[2 * n + 1];
        }
    }
    for (int off = 32; off > 0; off >>= 1) v += __shfl_down(v, off);
    __shared__ double sm[4];
    int lane = threadIdx.x & 63, wid = threadIdx.x >> 6;
    if (lane == 0) sm[wid] = v;
    __syncthreads();
    if (threadIdx.x == 0) {
        double sum = sm[0] + sm[1] + sm[2] + sm[3];
        unsafeAtomicAdd(dacc, sum);   // fire-and-forget; end-of-kernel drains it
    }
}

// separate tiny kernel: stream order + dispatch-boundary visibility (proven r15)
__global__ void k_out(const double* __restrict__ dacc, const float* __restrict__ mlp_b,
                      float* __restrict__ out) {
    double logit = __hip_atomic_load(dacc, __ATOMIC_ACQUIRE, __HIP_MEMORY_SCOPE_AGENT) +
                   (double)mlp_b[0];
    out[0] = (float)(1.0 / (1.0 + exp(-logit)));
}

extern "C" void kernel_launch(void* const* d_in, const int* in_sizes, int n_in,
                              void* d_out, int out_size, void* d_ws, size_t ws_size,
                              hipStream_t stream) {
    const float2* h    = (const float2*)d_in[0];
    const int*   src   = (const int*)d_in[1];
    const int*   dst   = (const int*)d_in[2];
    const float* fc1   = (const float*)d_in[3];
    const float* attn1 = (const float*)d_in[4];
    const float* fc2   = (const float*)d_in[5];
    const float* attn2 = (const float*)d_in[6];
    const float* mlp_w = (const float*)d_in[7];
    const float* mlp_b = (const float*)d_in[8];
    float* out = (float*)d_out;

    unsigned* ws      = (unsigned*)d_ws;
    double*   dacc    = (double*)d_ws;
    float*    uv      = (float*)(ws + W_UV);
    unsigned* cur     = ws + W_CUR;
    unsigned* nodeoff = ws + W_NOFF;
    unsigned* nodecnt = ws + W_NCNT;
    unsigned* meta    = ws + W_META;
    float2*   z2      = (float2*)(ws + W_Z2);

    const int NGG = (NN * GL + 255) / 256;      // 6250 blocks for gat kernels

    hipLaunchKernelGGL(k_init, dim3(1), dim3(264), 0, stream, ws, fc1, attn1);
    hipLaunchKernelGGL(k_scatter, dim3(NBLK_SC), dim3(SCT), 0, stream,
                       src, dst, meta, cur);
    hipLaunchKernelGGL(k_sort, dim3(NB), dim3(SCT), 0, stream,
                       meta, cur, nodeoff, nodecnt);
    hipLaunchKernelGGL(k_gat1, dim3(NGG), dim3(256), 0, stream,
                       meta, nodeoff, nodecnt, (const float2*)h, uv, fc1, fc2, z2);
    hipLaunchKernelGGL(k_gat2, dim3(NGG), dim3(256), 0, stream,
                       meta, nodeoff, nodecnt, (const float2*)z2, attn2, mlp_w, dacc);
    hipLaunchKernelGGL(k_out, dim3(1), dim3(1), 0, stream, dacc, mlp_b, out);
}

// Round 23
// 238.663 us; speedup vs baseline: 1.5761x; 1.1722x over previous
//
#include <hip/hip_runtime.h>
#include <hip/hip_bf16.h>
#include <math.h>

#define NN 200000
#define NE 6400000

#define BNODES 782                     // nodes per bucket (NB = 256 = #CUs)
#define NB 256
#define CAP 27648                      // 27*1024; mean 25000 -> +16 sigma
#define NBLK_SC 256
#define SCT 1024                       // scatter/sort block threads (16 waves)
#define CHUNK (NE / NBLK_SC)           // 25000; 25 iters/thread
#define SREG 27                        // sort: CAP/SCT register records/thread

// ---- workspace layout (4-byte words) ----
#define W_DACC 0                       // double (2 words)
#define W_UV   4                       // 8 floats
#define W_CUR  16                      // NB uints
#define W_NOFF 1024                    // NN uints
#define W_NCNT (W_NOFF + NN)           // NN uints
#define W_META (W_NCNT + NN)           // NB*CAP u32: sn(18b) | dl(10b)<<18
#define W_Z2   (W_META + NB*CAP)       // 2*NN f32
#define W_TOTAL (W_Z2 + 2*NN)          // ~7.9M words = 31.5 MB

// init + prep merged: zero dacc/cur, compute uv from fc1/attn1
__global__ void k_init(unsigned* __restrict__ ws, const float* __restrict__ fc1,
                       const float* __restrict__ attn1) {
    int t = threadIdx.x;
    if (t == 0) *(double*)ws = 0.0;
    if (t < NB) ws[W_CUR + t] = 0u;
    if (t >= 256 && t < 264) {
        int q = t - 256;
        int hh = q >> 2, r = q & 3, i = r & 1, isv = r >> 1;
        double s = 0.0;
        for (int o = 0; o < 16; ++o)
            s += (double)fc1[hh * 32 + i * 16 + o] * (double)attn1[hh * 32 + isv * 16 + o];
        ((float*)(ws + W_UV))[q] = (float)s;
    }
}

// radix partition by dst bucket (b = d/782), 4B meta records, ONE LDS atomic/edge.
__launch_bounds__(SCT)
__global__ void k_scatter(const int* __restrict__ src, const int* __restrict__ dst,
                          unsigned* __restrict__ meta, unsigned* __restrict__ cur) {
    __shared__ unsigned cnt[NB], gbase[NB];           // 2 KB
    for (int i = threadIdx.x; i < NB; i += SCT) cnt[i] = 0u;
    __syncthreads();
    int beg = blockIdx.x * CHUNK;
    unsigned pack[25];                                // d(18b) | rank(14b)<<18
#pragma unroll
    for (int k = 0; k < 25; ++k) {
        int j = k * SCT + threadIdx.x;
        pack[k] = 0xFFFFFFFFu;                        // d-field 0x3FFFF impossible (d<200000)
        if (j < CHUNK) {
            unsigned d = (unsigned)__builtin_nontemporal_load(dst + beg + j);
            unsigned rank = atomicAdd(&cnt[d / BNODES], 1u);   // count == rank
            pack[k] = d | (rank << 18);
        }
    }
    __syncthreads();
    for (int i = threadIdx.x; i < NB; i += SCT)
        gbase[i] = cnt[i] ? atomicAdd(&cur[i], cnt[i]) : 0u;
    __syncthreads();
#pragma unroll
    for (int k = 0; k < 25; ++k) {
        if (pack[k] != 0xFFFFFFFFu) {
            int j = k * SCT + threadIdx.x;
            unsigned d = pack[k] & 0x3FFFFu;
            unsigned b = d / BNODES;
            unsigned dl = d - b * BNODES;
            unsigned slot = gbase[b] + (pack[k] >> 18);
            if (slot < CAP) {
                unsigned sn = (unsigned)__builtin_nontemporal_load(src + beg + j);
                meta[(size_t)b * CAP + slot] = sn | (dl << 18);
            }
        }
    }
}

// in-place counting sort by node within each bucket; 256 blocks (1/CU, balanced);
// records staged in registers (27/thread, static); ONE LDS atomic/edge.
__launch_bounds__(SCT)
__global__ void k_sort(unsigned* __restrict__ meta, const unsigned* __restrict__ cur,
                       unsigned* __restrict__ nodeoff, unsigned* __restrict__ nodecnt) {
    __shared__ unsigned hist[BNODES], base[BNODES], scan[BNODES];   // 9.4 KB
    int b = blockIdx.x, t = threadIdx.x;
    size_t boff = (size_t)b * CAP;
    int cnt = min((int)cur[b], CAP);
    for (int i = t; i < BNODES; i += SCT) hist[i] = 0u;
    __syncthreads();
    unsigned rm[SREG], rr[SREG];
#pragma unroll
    for (int k = 0; k < SREG; ++k) {
        int i = k * SCT + t;
        rm[k] = 0xFFFFFFFFu;
        rr[k] = 0u;
        if (i < cnt) {
            rm[k] = meta[boff + i];
            rr[k] = atomicAdd(&hist[rm[k] >> 18], 1u);    // rank within node
        }
    }
    asm volatile("s_waitcnt vmcnt(0)" ::: "memory");      // all reads before any write
    __syncthreads();
    if (t < BNODES) scan[t] = hist[t];
    __syncthreads();
    for (int d = 1; d < BNODES; d <<= 1) {                // Hillis-Steele inclusive scan
        unsigned v = 0u;
        if (t < BNODES && t >= d) v = scan[t - d];
        __syncthreads();
        if (t < BNODES) scan[t] += v;
        __syncthreads();
    }
    int nb = b * BNODES;
    int nn = min(BNODES, NN - nb);
    if (t < BNODES) {
        unsigned ex = scan[t] - hist[t];                  // exclusive base
        base[t] = ex;
        if (t < nn) {
            nodeoff[nb + t] = (unsigned)boff + ex;
            nodecnt[nb + t] = hist[t];
        }
    }
    __syncthreads();
#pragma unroll
    for (int k = 0; k < SREG; ++k)
        if (rm[k] != 0xFFFFFFFFu)
            meta[boff + base[rm[k] >> 18] + rr[k]] = rm[k];
}

// layer-1 + node finalize fused: thread-per-node (MSHR-saturating serial gather),
// zero atomics; h gathers hit L2-resident 1.6 MB h.
__global__ void k_gat1(const unsigned* __restrict__ meta, const unsigned* __restrict__ nodeoff,
                       const unsigned* __restrict__ nodecnt, const float2* __restrict__ h,
                       const float* __restrict__ uv, const float* __restrict__ fc1,
                       const float* __restrict__ fc2, float2* __restrict__ z2) {
    int n = blockIdx.x * blockDim.x + threadIdx.x;
    if (n >= NN) return;
    float u00 = uv[0], u10 = uv[1], v00 = uv[2], v10 = uv[3];
    float u01 = uv[4], u11 = uv[5], v01 = uv[6], v11 = uv[7];
    float2 hd = h[n];
    float c0 = fmaf(hd.x, v00, hd.y * v10);
    float c1 = fmaf(hd.x, v01, hd.y * v11);
    unsigned off = nodeoff[n];
    int cnt = (int)nodecnt[n];
    float s0 = 0.f, s1 = 0.f, s2 = 0.f, s3 = 0.f, s4 = 0.f, s5 = 0.f;
#pragma unroll 4
    for (int k = 0; k < cnt; ++k) {
        unsigned m = meta[(size_t)off + k];
        float2 hs = h[m & 0x3FFFF];
        float e0 = fmaf(hs.x, u00, fmaf(hs.y, u10, c0));
        float e1 = fmaf(hs.x, u01, fmaf(hs.y, u11, c1));
        e0 = e0 >= 0.f ? e0 : 0.01f * e0;
        e1 = e1 >= 0.f ? e1 : 0.01f * e1;
        float ex0 = __expf(e0);
        float ex1 = __expf(e1);
        s0 += ex0; s1 += ex0 * hs.x; s2 += ex0 * hs.y;
        s3 += ex1; s4 += ex1 * hs.x; s5 += ex1 * hs.y;
    }
    float z0 = 0.f, z1 = 0.f;
#pragma unroll
    for (int o = 0; o < 16; ++o) {      // softmax div + elu + z2 = x @ fc2
        float t0 = s0 > 0.f ? (s1 * fc1[o]      + s2 * fc1[16 + o]) / s0 : 0.f;
        float t1 = s3 > 0.f ? (s4 * fc1[32 + o] + s5 * fc1[48 + o]) / s3 : 0.f;
        float x0 = t0 > 0.f ? t0 : expm1f(t0);
        float x1 = t1 > 0.f ? t1 : expm1f(t1);
        z0 += x0 * fc2[2 * o]     + x1 * fc2[2 * (16 + o)];
        z1 += x0 * fc2[2 * o + 1] + x1 * fc2[2 * (16 + o) + 1];
    }
    z2[n] = make_float2(z0, z1);
}

// layer-2 + MLP dot fused: thread-per-node; f64 block reduce; ONE fire-and-forget
// dacc atomic per block (no waitcnt / no counter: block retires immediately).
__global__ void k_gat2(const unsigned* __restrict__ meta, const unsigned* __restrict__ nodeoff,
                       const unsigned* __restrict__ nodecnt, const float2* __restrict__ z2,
                       const float* __restrict__ attn2, const float* __restrict__ mlp_w,
                       double* __restrict__ dacc) {
    int n = blockIdx.x * blockDim.x + threadIdx.x;
    double v = 0.0;
    if (n < NN) {
        float a0 = attn2[0], a1 = attn2[1], a2 = attn2[2], a3 = attn2[3];
        float2 zd = z2[n];
        float cd = fmaf(zd.x, a2, zd.y * a3);
        unsigned off = nodeoff[n];
        int cnt = (int)nodecnt[n];
        float s0 = 0.f, s1 = 0.f, s2 = 0.f;
#pragma unroll 4
        for (int k = 0; k < cnt; ++k) {
            unsigned m = meta[(size_t)off + k];
            float2 zs = z2[m & 0x3FFFF];
            float e = fmaf(zs.x, a0, fmaf(zs.y, a1, cd));
            e = e >= 0.f ? e : 0.01f * e;
            float ex = __expf(e - 48.f);   // const shift cancels; e<=~88, den>=deg*e^-49
            s0 += ex; s1 += ex * zs.x; s2 += ex * zs.y;
        }
        float x0 = s0 > 0.f ? s1 / s0 : 0.f;
        float x1 = s0 > 0.f ? s2 / s0 : 0.f;
        v = (double)x0 * (double)mlp_w[2 * n] + (double)x1 * (double)mlp_w[2 * n + 1];
    }
    for (int off = 32; off > 0; off >>= 1) v += __shfl_down(v, off);
    __shared__ double sm[4];
    int lane = threadIdx.x & 63, wid = threadIdx.x >> 6;
    if (lane == 0) sm[wid] = v;
    __syncthreads();
    if (threadIdx.x == 0) {
        double sum = sm[0] + sm[1] + sm[2] + sm[3];
        unsafeAtomicAdd(dacc, sum);   // fire-and-forget; end-of-kernel drains it
    }
}

// separate tiny kernel: dispatch-boundary gives visibility of all dacc adds.
__global__ void k_out(const double* __restrict__ dacc, const float* __restrict__ mlp_b,
                      float* __restrict__ out) {
    double logit = __hip_atomic_load(dacc, __ATOMIC_ACQUIRE, __HIP_MEMORY_SCOPE_AGENT) +
                   (double)mlp_b[0];
    out[0] = (float)(1.0 / (1.0 + exp(-logit)));
}

extern "C" void kernel_launch(void* const* d_in, const int* in_sizes, int n_in,
                              void* d_out, int out_size, void* d_ws, size_t ws_size,
                              hipStream_t stream) {
    const float2* h    = (const float2*)d_in[0];
    const int*   src   = (const int*)d_in[1];
    const int*   dst   = (const int*)d_in[2];
    const float* fc1   = (const float*)d_in[3];
    const float* attn1 = (const float*)d_in[4];
    const float* fc2   = (const float*)d_in[5];
    const float* attn2 = (const float*)d_in[6];
    const float* mlp_w = (const float*)d_in[7];
    const float* mlp_b = (const float*)d_in[8];
    float* out = (float*)d_out;

    unsigned* ws      = (unsigned*)d_ws;
    double*   dacc    = (double*)d_ws;
    float*    uv      = (float*)(ws + W_UV);
    unsigned* cur     = ws + W_CUR;
    unsigned* nodeoff = ws + W_NOFF;
    unsigned* nodecnt = ws + W_NCNT;
    unsigned* meta    = ws + W_META;
    float2*   z2      = (float2*)(ws + W_Z2);

    const int NG = (NN + 255) / 256;            // 782 blocks for gat kernels

    hipLaunchKernelGGL(k_init, dim3(1), dim3(264), 0, stream, ws, fc1, attn1);
    hipLaunchKernelGGL(k_scatter, dim3(NBLK_SC), dim3(SCT), 0, stream,
                       src, dst, meta, cur);
    hipLaunchKernelGGL(k_sort, dim3(NB), dim3(SCT), 0, stream,
                       meta, cur, nodeoff, nodecnt);
    hipLaunchKernelGGL(k_gat1, dim3(NG), dim3(256), 0, stream,
                       meta, nodeoff, nodecnt, (const float2*)h, uv, fc1, fc2, z2);
    hipLaunchKernelGGL(k_gat2, dim3(NG), dim3(256), 0, stream,
                       meta, nodeoff, nodecnt, (const float2*)z2, attn2, mlp_w, dacc);
    hipLaunchKernelGGL(k_out, dim3(1), dim3(1), 0, stream, dacc, mlp_b, out);
}